// Round 4
// baseline (277.505 us; speedup 1.0000x reference)
//
#include <hip/hip_runtime.h>

// CRF log-partition, MI355X — R4: single-wave, barrier-free, E streamed from LDS.
// R3 lesson (re-confirmed): >~64 E-dwords/lane in registers -> AGPR parking
// (VGPR_Count capped 132, accvgpr shuttles, 2.5x regression). So the full
// 128-dot per lane keeps E in LDS (f16-packed, 40KB) and STREAMS it each step:
//  - lane p owns tags {2p,2p+1}; per step: 128 fdot2 (the f16-FLOP floor),
//    fed by 32 ds_read_b128 of E + 16 broadcast ds_read_b128 of state
//  - E layout: per-lane 40 slots of 16B at base p*640B; logical chunk j at
//    slot j+(p&7)  -> each read spreads across all 8 bank quads (optimal),
//    and the shift folds into the per-lane base: reads use IMMEDIATE offsets
//    (zero per-step address VALU)
//  - state: 64 packed-f16 pair-dwords; lane writes its own dword, reads all
//    as wave-uniform broadcast b128 -> conflict-free
//  - ONE wave per block: NO s_barrier, no DPP combine, no divergent writer;
//    a single s_waitcnt lgkmcnt(0) per step orders the state RAW
// Bidi split (R2, validated) retained: 128 blocks = 64 fwd + 64 bwd chains;
// crf_combine does dot(alpha_m, x_m) + log. Renorm identical to R1-R3
// (f16 exponent of state[0] folded into exp2 arg; o += eS exact).

#define LOG2E 1.4426950408889634f
#define LN2   0.6931471805599453f

#define LGKM0() asm volatile("s_waitcnt lgkmcnt(0)" ::: "memory")

typedef float    f2 __attribute__((ext_vector_type(2)));
typedef float    f4 __attribute__((ext_vector_type(4)));
typedef _Float16 h2 __attribute__((ext_vector_type(2)));

#define PKRTZ(a, b) __builtin_bit_cast(h2, __builtin_amdgcn_cvt_pkrtz((a), (b)))
#define H2F(x)      __builtin_bit_cast(float, (x))
#define F2H(x)      __builtin_bit_cast(h2, (x))

__global__ __launch_bounds__(64)
__attribute__((amdgpu_waves_per_eu(1, 1)))
void crf_halves(
    const float* __restrict__ emissions,   // [64, 512, 128]
    const float* __restrict__ transitions, // [128, 128]
    const float* __restrict__ start_t,     // [128]
    const float* __restrict__ end_t,       // [128]
    const int*   __restrict__ lengths,     // [64]
    float* __restrict__ wsV,               // [2][64][128] half-vectors
    int*   __restrict__ wsO)               // [2][64] exponent accumulators
{
    constexpr int N = 128;
    constexpr int L = 512;
    const int  bid = blockIdx.x;
    const bool isf = bid < 64;
    const int  b   = isf ? bid : bid - 64;
    const int  p   = threadIdx.x;     // lane = tag pair {2p, 2p+1}
    const int  swz = p & 7;           // slot shift for bank spread

    // E: 64 lanes x 40 slots x 16B (slots j+swz, j in [0,32)) = 40KB.
    // Lane stride 160 dwords (160%32==0: bank pattern set purely by slot).
    __shared__ alignas(16) float elds[64 * 160];
    // state: packed f16 pairs, double-buffered; writes 1 dword/lane,
    // reads wave-uniform broadcast b128.
    __shared__ alignas(16) float pbuf[2][64];

    f4* ew = reinterpret_cast<f4*>(elds + (size_t)p * 160 + 4 * swz);

    // ---- one-time E build. Chunk j holds pair-dwords m=2j,2j+1 as
    // {EA_2j, EB_2j, EA_2j+1, EB_2j+1}.
    // fwd: EA_m=(e^T[2m][2p],   e^T[2m+1][2p]),  EB_m: col 2p+1
    // bwd: EA_m=(e^T[2p][2m],   e^T[2p][2m+1]),  EB_m: row 2p+1
    if (isf) {
        const float* tb = transitions + 2 * p;
        #pragma unroll
        for (int j = 0; j < 32; ++j) {
            f2 r0 = *reinterpret_cast<const f2*>(tb + (size_t)(4 * j + 0) * N);
            f2 r1 = *reinterpret_cast<const f2*>(tb + (size_t)(4 * j + 1) * N);
            f2 r2 = *reinterpret_cast<const f2*>(tb + (size_t)(4 * j + 2) * N);
            f2 r3 = *reinterpret_cast<const f2*>(tb + (size_t)(4 * j + 3) * N);
            h2 ea0 = PKRTZ(__builtin_amdgcn_exp2f(r0.x * LOG2E),
                           __builtin_amdgcn_exp2f(r1.x * LOG2E));
            h2 eb0 = PKRTZ(__builtin_amdgcn_exp2f(r0.y * LOG2E),
                           __builtin_amdgcn_exp2f(r1.y * LOG2E));
            h2 ea1 = PKRTZ(__builtin_amdgcn_exp2f(r2.x * LOG2E),
                           __builtin_amdgcn_exp2f(r3.x * LOG2E));
            h2 eb1 = PKRTZ(__builtin_amdgcn_exp2f(r2.y * LOG2E),
                           __builtin_amdgcn_exp2f(r3.y * LOG2E));
            f4 chunk; chunk.x = H2F(ea0); chunk.y = H2F(eb0);
                      chunk.z = H2F(ea1); chunk.w = H2F(eb1);
            ew[j] = chunk;
        }
    } else {
        const float* ra_ = transitions + (size_t)(2 * p) * N;
        const float* rb_ = ra_ + N;
        #pragma unroll
        for (int j = 0; j < 32; ++j) {
            f4 ta = *reinterpret_cast<const f4*>(ra_ + 4 * j);
            f4 tb_ = *reinterpret_cast<const f4*>(rb_ + 4 * j);
            h2 ea0 = PKRTZ(__builtin_amdgcn_exp2f(ta.x * LOG2E),
                           __builtin_amdgcn_exp2f(ta.y * LOG2E));
            h2 ea1 = PKRTZ(__builtin_amdgcn_exp2f(ta.z * LOG2E),
                           __builtin_amdgcn_exp2f(ta.w * LOG2E));
            h2 eb0 = PKRTZ(__builtin_amdgcn_exp2f(tb_.x * LOG2E),
                           __builtin_amdgcn_exp2f(tb_.y * LOG2E));
            h2 eb1 = PKRTZ(__builtin_amdgcn_exp2f(tb_.z * LOG2E),
                           __builtin_amdgcn_exp2f(tb_.w * LOG2E));
            f4 chunk; chunk.x = H2F(ea0); chunk.y = H2F(eb0);
                      chunk.z = H2F(ea1); chunk.w = H2F(eb1);
            ew[j] = chunk;
        }
    }

    const int len = lengths[b];
    const int m   = (len - 1) >> 1;
    const float* eb = emissions + (size_t)b * L * N;

    // step schedule (validated in R2/R3)
    int n_steps, e0, dstep; bool zfinal;
    if (isf) {
        n_steps = m; e0 = 1; dstep = 1; zfinal = false;
    } else {
        int total = len - 1 - m;
        n_steps = total > 0 ? total - 1 : 0;
        e0 = len - 2; if (e0 < 0) e0 = 0;
        dstep = -1;
        zfinal = total > 0;
    }

    // ---- init state
    int o = 0, cur = 0;
    float qA, qB;
    {
        const float* base = isf ? start_t : end_t;
        f2 bt = *reinterpret_cast<const f2*>(base + 2 * p);
        f2 ev;
        if (isf)         ev = *reinterpret_cast<const f2*>(eb + 2 * p);
        else if (zfinal) ev = *reinterpret_cast<const f2*>(eb + (size_t)(len - 1) * N + 2 * p);
        else           { ev.x = 0.f; ev.y = 0.f; }
        qA = __builtin_amdgcn_exp2f((bt.x + ev.x) * LOG2E);
        qB = __builtin_amdgcn_exp2f((bt.y + ev.y) * LOG2E);
        pbuf[0][p] = H2F(PKRTZ(qA, qB));
    }
    LGKM0();   // E writes + state write visible to own wave

    auto eidx = [&](int n) {
        int nn = (n < n_steps) ? n : (n_steps - 1);
        if (nn < 0) nn = 0;
        return e0 + dstep * nn;
    };
    auto ldE = [&](int tt) {
        return *reinterpret_cast<const f2*>(eb + (size_t)tt * N + 2 * p);
    };

    const f4* ebase = reinterpret_cast<const f4*>(elds + (size_t)p * 160 + 4 * swz);

    auto STEP = [&](f2 ecur) {
        // renorm source: state[0] (broadcast b32)
        float q0w = pbuf[cur][0];
        const f4* pv = reinterpret_cast<const f4*>(&pbuf[cur][0]);

        unsigned u0 = __float_as_uint(q0w);
        int eS = (int)((u0 >> 10) & 0x1Fu) - 15;
        o += eS;
        float feS = (float)eS;
        float esA = __builtin_amdgcn_exp2f(ecur.x * LOG2E - feS);
        float esB = __builtin_amdgcn_exp2f(ecur.y * LOG2E - feS);

        // 128 fdot2 over all 64 pair-dwords; E streamed 2 chunks / 4 dwords
        // per state-b128. 8 chains (4 per column), depth 16.
        float aA[4] = {0.f, 0.f, 0.f, 0.f};
        float aB[4] = {0.f, 0.f, 0.f, 0.f};
        #pragma unroll
        for (int sc = 0; sc < 16; ++sc) {
            f4 P  = pv[sc];                 // pair-dwords m = 4sc .. 4sc+3
            f4 e0v = ebase[2 * sc];         // m = 4sc, 4sc+1
            f4 e1v = ebase[2 * sc + 1];     // m = 4sc+2, 4sc+3
            h2 p0 = F2H(P.x), p1 = F2H(P.y), p2 = F2H(P.z), p3 = F2H(P.w);
            aA[0] = __builtin_amdgcn_fdot2(p0, F2H(e0v.x), aA[0], false);
            aB[0] = __builtin_amdgcn_fdot2(p0, F2H(e0v.y), aB[0], false);
            aA[1] = __builtin_amdgcn_fdot2(p1, F2H(e0v.z), aA[1], false);
            aB[1] = __builtin_amdgcn_fdot2(p1, F2H(e0v.w), aB[1], false);
            aA[2] = __builtin_amdgcn_fdot2(p2, F2H(e1v.x), aA[2], false);
            aB[2] = __builtin_amdgcn_fdot2(p2, F2H(e1v.y), aB[2], false);
            aA[3] = __builtin_amdgcn_fdot2(p3, F2H(e1v.z), aA[3], false);
            aB[3] = __builtin_amdgcn_fdot2(p3, F2H(e1v.w), aB[3], false);
        }
        float dA = (aA[0] + aA[1]) + (aA[2] + aA[3]);
        float dB = (aB[0] + aB[1]) + (aB[2] + aB[3]);

        qA = esA * dA;
        qB = esB * dB;
        cur ^= 1;
        pbuf[cur][p] = H2F(PKRTZ(qA, qB));
        LGKM0();   // single wave: RAW ordering, no s_barrier
    };

    // ---- main loop: distance-4 emission prefetch ring, 4-way unroll
    f2 ra = ldE(eidx(0));
    f2 rb = ldE(eidx(1));
    f2 rc = ldE(eidx(2));
    f2 rd = ldE(eidx(3));

    int n = 0;
    while (n < n_steps) {
        STEP(ra); ra = ldE(eidx(n + 4)); ++n; if (n >= n_steps) break;
        STEP(rb); rb = ldE(eidx(n + 4)); ++n; if (n >= n_steps) break;
        STEP(rc); rc = ldE(eidx(n + 4)); ++n; if (n >= n_steps) break;
        STEP(rd); rd = ldE(eidx(n + 4)); ++n;
    }
    if (zfinal) {              // x_m = E * w_{m+1}: zero-emission step
        f2 z; z.x = 0.f; z.y = 0.f;
        STEP(z);
    }

    // ---- write half-result: f32 pair per lane + exponent accumulator
    float* wv = wsV + (size_t)((isf ? 0 : 64) + b) * 128;
    f2 q; q.x = qA; q.y = qB;
    *reinterpret_cast<f2*>(wv + 2 * p) = q;
    if (p == 0) wsO[(isf ? 0 : 64) + b] = o;
}

__global__ __launch_bounds__(64)
void crf_combine(const float* __restrict__ wsV, const int* __restrict__ wsO,
                 const int* __restrict__ lengths, float* __restrict__ out)
{
    const int b = blockIdx.x;
    const int g = threadIdx.x;   // 64 lanes, pair {2g,2g+1}
    f2 a = *reinterpret_cast<const f2*>(wsV + (size_t)b * 128 + 2 * g);
    f2 x = *reinterpret_cast<const f2*>(wsV + (size_t)(64 + b) * 128 + 2 * g);
    float v = a.x * x.x + a.y * x.y;
    #pragma unroll
    for (int s = 1; s < 64; s <<= 1) v += __shfl_xor(v, s);
    if (g == 0)
        out[b] = LN2 * ((float)(wsO[b] + wsO[64 + b]) +
                        __builtin_amdgcn_logf(v));
}

extern "C" void kernel_launch(void* const* d_in, const int* in_sizes, int n_in,
                              void* d_out, int out_size, void* d_ws, size_t ws_size,
                              hipStream_t stream) {
    const float* emissions   = (const float*)d_in[0];
    const float* transitions = (const float*)d_in[1];
    const float* start_t     = (const float*)d_in[2];
    const float* end_t       = (const float*)d_in[3];
    const int*   lengths     = (const int*)d_in[4];
    float* out = (float*)d_out;

    float* wsV = (float*)d_ws;                                   // [2][64][128]
    int*   wsO = (int*)((char*)d_ws + 2 * 64 * 128 * sizeof(float)); // [2][64]

    crf_halves<<<dim3(128), dim3(64), 0, stream>>>(
        emissions, transitions, start_t, end_t, lengths, wsV, wsO);
    crf_combine<<<dim3(64), dim3(64), 0, stream>>>(wsV, wsO, lengths, out);
}

// Round 5
// 184.146 us; speedup vs baseline: 1.5070x; 1.5070x over previous
//
#include <hip/hip_runtime.h>

// CRF log-partition, MI355X — R5: R2 structure + TWO chains per block.
// R3 lesson: >~64 E-dwords/lane in regs -> AGPR parking. R4 lesson: streaming
// E from LDS = 32KB/step -> >=256cyc LDS BW + 8-way conflicts, no TLP. The
// 4-wave R2 step (E spread across waves, 32 VGPR/lane) is the right shape;
// its cost is ~160 cyc issue + ~480 cyc stall (state LDS RT + barrier+skew)
// PER ROUND. This version advances two same-direction chains per round:
//   block s in [0,32): fwd chains of seqs s and s+32 (SAME E tile)
//   block 32+s       : bwd chains of seqs s and s+32
// Per round: read state1+state2 (independent), dot1 (overlaps read2 latency),
// dot2, commit both, write both, ONE barrier. ~2x steps per stall.
// Wall rounds still max_b ceil((len_b-1)/2) — pairing costs nothing.
// STEP math is bit-identical to R2 per chain (validated): f16 LDS state,
// 4x ds_read_b128 + b32 broadcast, 32 fdot2 (4 chains), quad DPP combine,
// f16-exponent renorm folded into exp2, lgkm-only barrier, frozen chains
// rewrite old state. Bidi split + crf_combine unchanged.

#define LOG2E 1.4426950408889634f
#define LN2   0.6931471805599453f

#define LDS_BARRIER() asm volatile("s_waitcnt lgkmcnt(0)\n\ts_barrier" ::: "memory")

typedef float    f2 __attribute__((ext_vector_type(2)));
typedef _Float16 h2 __attribute__((ext_vector_type(2)));

#define PKRTZ(a, b) __builtin_bit_cast(h2, __builtin_amdgcn_cvt_pkrtz((a), (b)))

template <int CTRL>
__device__ __forceinline__ float dpp_f(float x) {
    return __int_as_float(
        __builtin_amdgcn_mov_dpp(__float_as_int(x), CTRL, 0xF, 0xF, false));
}
// quad_perm codes: xor1 = 0xB1, xor2 = 0x4E

__global__ __launch_bounds__(256)
__attribute__((amdgpu_waves_per_eu(1, 1)))
void crf_halves(
    const float* __restrict__ emissions,   // [64, 512, 128]
    const float* __restrict__ transitions, // [128, 128]
    const float* __restrict__ start_t,     // [128]
    const float* __restrict__ end_t,       // [128]
    const int*   __restrict__ lengths,     // [64]
    float* __restrict__ wsV,               // [2][64][128] half-vectors
    int*   __restrict__ wsO)               // [2][64] exponent accumulators
{
    constexpr int N = 128;
    constexpr int L = 512;
    const int  bid = blockIdx.x;      // 64 blocks
    const bool isf = bid < 32;
    const int  s   = isf ? bid : bid - 32;
    const int  b1  = s;
    const int  b2  = s + 32;
    const int  tid = threadIdx.x;
    const int  g   = tid >> 2;        // tag pair {2g, 2g+1}
    const int  k   = tid & 3;         // i-chunk: tags [32k, 32k+32)

    __shared__ alignas(16) float pb1[2][80];
    __shared__ alignas(16) float pb2[2][80];

    h2 EA_0,  EA_1,  EA_2,  EA_3,  EA_4,  EA_5,  EA_6,  EA_7;
    h2 EA_8,  EA_9,  EA_10, EA_11, EA_12, EA_13, EA_14, EA_15;
    h2 EB_0,  EB_1,  EB_2,  EB_3,  EB_4,  EB_5,  EB_6,  EB_7;
    h2 EB_8,  EB_9,  EB_10, EB_11, EB_12, EB_13, EB_14, EB_15;
    if (isf) {
        const float* tb = transitions + (size_t)(32 * k) * N + 2 * g;
#define INIT_F(m)                                                              \
        {                                                                      \
            f2 r0 = *reinterpret_cast<const f2*>(tb + (size_t)(2 * (m)) * N);  \
            f2 r1 = *reinterpret_cast<const f2*>(tb + (size_t)(2 * (m) + 1) * N); \
            EA_##m = PKRTZ(__builtin_amdgcn_exp2f(r0.x * LOG2E),               \
                           __builtin_amdgcn_exp2f(r1.x * LOG2E));              \
            EB_##m = PKRTZ(__builtin_amdgcn_exp2f(r0.y * LOG2E),               \
                           __builtin_amdgcn_exp2f(r1.y * LOG2E));              \
        }
        INIT_F(0)  INIT_F(1)  INIT_F(2)  INIT_F(3)
        INIT_F(4)  INIT_F(5)  INIT_F(6)  INIT_F(7)
        INIT_F(8)  INIT_F(9)  INIT_F(10) INIT_F(11)
        INIT_F(12) INIT_F(13) INIT_F(14) INIT_F(15)
#undef INIT_F
    } else {
        const float* ra_ = transitions + (size_t)(2 * g) * N + 32 * k;
        const float* rb_ = transitions + (size_t)(2 * g + 1) * N + 32 * k;
#define INIT_B(m)                                                              \
        {                                                                      \
            f2 r0 = *reinterpret_cast<const f2*>(ra_ + 2 * (m));               \
            f2 r1 = *reinterpret_cast<const f2*>(rb_ + 2 * (m));               \
            EA_##m = PKRTZ(__builtin_amdgcn_exp2f(r0.x * LOG2E),               \
                           __builtin_amdgcn_exp2f(r0.y * LOG2E));              \
            EB_##m = PKRTZ(__builtin_amdgcn_exp2f(r1.x * LOG2E),               \
                           __builtin_amdgcn_exp2f(r1.y * LOG2E));              \
        }
        INIT_B(0)  INIT_B(1)  INIT_B(2)  INIT_B(3)
        INIT_B(4)  INIT_B(5)  INIT_B(6)  INIT_B(7)
        INIT_B(8)  INIT_B(9)  INIT_B(10) INIT_B(11)
        INIT_B(12) INIT_B(13) INIT_B(14) INIT_B(15)
#undef INIT_B
    }

    const int len1 = lengths[b1];
    const int len2 = lengths[b2];
    const int m1   = (len1 - 1) >> 1;
    const int m2   = (len2 - 1) >> 1;
    const float* eb1 = emissions + (size_t)b1 * L * N;
    const float* eb2 = emissions + (size_t)b2 * L * N;

    int ns1, e01, total1, ns2, e02, total2, dstep;
    if (isf) {
        dstep = 1;
        ns1 = m1; e01 = 1; total1 = m1;
        ns2 = m2; e02 = 1; total2 = m2;
    } else {
        dstep = -1;
        int tt1 = len1 - 1 - m1;
        ns1 = tt1 > 0 ? tt1 - 1 : 0; e01 = len1 - 2 < 0 ? 0 : len1 - 2; total1 = tt1;
        int tt2 = len2 - 1 - m2;
        ns2 = tt2 > 0 ? tt2 - 1 : 0; e02 = len2 - 2 < 0 ? 0 : len2 - 2; total2 = tt2;
    }

    int o1 = 0, o2 = 0, cur = 0;
    float qA1, qB1, qA2, qB2;
    {
        const float* base = isf ? start_t : end_t;
        f2 bt = *reinterpret_cast<const f2*>(base + 2 * g);
        f2 ev1, ev2;
        if (isf) {
            ev1 = *reinterpret_cast<const f2*>(eb1 + 2 * g);
            ev2 = *reinterpret_cast<const f2*>(eb2 + 2 * g);
        } else {
            if (len1 > 1) ev1 = *reinterpret_cast<const f2*>(eb1 + (size_t)(len1 - 1) * N + 2 * g);
            else        { ev1.x = 0.f; ev1.y = 0.f; }
            if (len2 > 1) ev2 = *reinterpret_cast<const f2*>(eb2 + (size_t)(len2 - 1) * N + 2 * g);
            else        { ev2.x = 0.f; ev2.y = 0.f; }
        }
        qA1 = __builtin_amdgcn_exp2f((bt.x + ev1.x) * LOG2E);
        qB1 = __builtin_amdgcn_exp2f((bt.y + ev1.y) * LOG2E);
        qA2 = __builtin_amdgcn_exp2f((bt.x + ev2.x) * LOG2E);
        qB2 = __builtin_amdgcn_exp2f((bt.y + ev2.y) * LOG2E);
        if (k == 0) {
            pb1[0][(g >> 4) * 20 + (g & 15)] = __builtin_bit_cast(float, PKRTZ(qA1, qB1));
            pb2[0][(g >> 4) * 20 + (g & 15)] = __builtin_bit_cast(float, PKRTZ(qA2, qB2));
        }
    }
    LDS_BARRIER();

    auto ei1 = [&](int n) {
        int nn = (n < ns1) ? n : (ns1 - 1);
        if (nn < 0) nn = 0;
        return e01 + dstep * nn;
    };
    auto ei2 = [&](int n) {
        int nn = (n < ns2) ? n : (ns2 - 1);
        if (nn < 0) nn = 0;
        return e02 + dstep * nn;
    };
    auto ldE1 = [&](int tt) {
        return *reinterpret_cast<const f2*>(eb1 + (size_t)tt * N + 2 * g);
    };
    auto ldE2 = [&](int tt) {
        return *reinterpret_cast<const f2*>(eb2 + (size_t)tt * N + 2 * g);
    };

    auto DOT = [&](const float4& Qa, const float4& Qb, const float4& Qc,
                   const float4& Qd, float& dA, float& dB) {
        float aA0 = 0.f, aA1 = 0.f, aB0 = 0.f, aB1 = 0.f;
#define D0(m_, Qc_)                                                            \
        {                                                                      \
            h2 pm = __builtin_bit_cast(h2, Qc_);                               \
            aA0 = __builtin_amdgcn_fdot2(pm, EA_##m_, aA0, false);             \
            aB0 = __builtin_amdgcn_fdot2(pm, EB_##m_, aB0, false);             \
        }
#define D1(m_, Qc_)                                                            \
        {                                                                      \
            h2 pm = __builtin_bit_cast(h2, Qc_);                               \
            aA1 = __builtin_amdgcn_fdot2(pm, EA_##m_, aA1, false);             \
            aB1 = __builtin_amdgcn_fdot2(pm, EB_##m_, aB1, false);             \
        }
        D0(0,  Qa.x) D1(1,  Qa.y) D0(2,  Qa.z) D1(3,  Qa.w)
        D0(4,  Qb.x) D1(5,  Qb.y) D0(6,  Qb.z) D1(7,  Qb.w)
        D0(8,  Qc.x) D1(9,  Qc.y) D0(10, Qc.z) D1(11, Qc.w)
        D0(12, Qd.x) D1(13, Qd.y) D0(14, Qd.z) D1(15, Qd.w)
#undef D0
#undef D1
        float dA_ = aA0 + aA1;
        float dB_ = aB0 + aB1;
        dA_ += dpp_f<0xB1>(dA_); dB_ += dpp_f<0xB1>(dB_);
        dA_ += dpp_f<0x4E>(dA_); dB_ += dpp_f<0x4E>(dB_);
        dA = dA_; dB = dB_;
    };

    auto ROUND = [&](f2 e1, f2 e2, int r) {
        float q0w1 = pb1[cur][0];
        const float4* pv1 = reinterpret_cast<const float4*>(&pb1[cur][k * 20]);
        float4 Qa1 = pv1[0], Qb1 = pv1[1], Qc1 = pv1[2], Qd1 = pv1[3];
        float q0w2 = pb2[cur][0];
        const float4* pv2 = reinterpret_cast<const float4*>(&pb2[cur][k * 20]);
        float4 Qa2 = pv2[0], Qb2 = pv2[1], Qc2 = pv2[2], Qd2 = pv2[3];

        float dA1, dB1, dA2, dB2;
        DOT(Qa1, Qb1, Qc1, Qd1, dA1, dB1);
        DOT(Qa2, Qb2, Qc2, Qd2, dA2, dB2);

        if (r < total1) {
            unsigned u0 = __float_as_uint(q0w1);
            int eS = (int)((u0 >> 10) & 0x1Fu) - 15;
            o1 += eS;
            float feS = (float)eS;
            f2 ec = e1;
            if (r >= ns1) { ec.x = 0.f; ec.y = 0.f; }
            qA1 = __builtin_amdgcn_exp2f(ec.x * LOG2E - feS) * dA1;
            qB1 = __builtin_amdgcn_exp2f(ec.y * LOG2E - feS) * dB1;
        }
        if (r < total2) {
            unsigned u0 = __float_as_uint(q0w2);
            int eS = (int)((u0 >> 10) & 0x1Fu) - 15;
            o2 += eS;
            float feS = (float)eS;
            f2 ec = e2;
            if (r >= ns2) { ec.x = 0.f; ec.y = 0.f; }
            qA2 = __builtin_amdgcn_exp2f(ec.x * LOG2E - feS) * dA2;
            qB2 = __builtin_amdgcn_exp2f(ec.y * LOG2E - feS) * dB2;
        }
        cur ^= 1;
        if (k == 0) {
            pb1[cur][(g >> 4) * 20 + (g & 15)] = __builtin_bit_cast(float, PKRTZ(qA1, qB1));
            pb2[cur][(g >> 4) * 20 + (g & 15)] = __builtin_bit_cast(float, PKRTZ(qA2, qB2));
        }
        LDS_BARRIER();
    };

    f2 ra1 = ldE1(ei1(0)), rb1 = ldE1(ei1(1)), rc1 = ldE1(ei1(2)), rd1 = ldE1(ei1(3));
    f2 ra2 = ldE2(ei2(0)), rb2 = ldE2(ei2(1)), rc2 = ldE2(ei2(2)), rd2 = ldE2(ei2(3));

    const int R = total1 > total2 ? total1 : total2;
    int r = 0;
    while (r < R) {
        ROUND(ra1, ra2, r); ra1 = ldE1(ei1(r + 4)); ra2 = ldE2(ei2(r + 4)); ++r; if (r >= R) break;
        ROUND(rb1, rb2, r); rb1 = ldE1(ei1(r + 4)); rb2 = ldE2(ei2(r + 4)); ++r; if (r >= R) break;
        ROUND(rc1, rc2, r); rc1 = ldE1(ei1(r + 4)); rc2 = ldE2(ei2(r + 4)); ++r; if (r >= R) break;
        ROUND(rd1, rd2, r); rd1 = ldE1(ei1(r + 4)); rd2 = ldE2(ei2(r + 4)); ++r;
    }

    {
        float* wv1 = wsV + (size_t)((isf ? 0 : 64) + b1) * 128;
        float* wv2 = wsV + (size_t)((isf ? 0 : 64) + b2) * 128;
        if (k == 0) {
            f2 q1; q1.x = qA1; q1.y = qB1;
            f2 q2; q2.x = qA2; q2.y = qB2;
            *reinterpret_cast<f2*>(wv1 + 2 * g) = q1;
            *reinterpret_cast<f2*>(wv2 + 2 * g) = q2;
        }
        if (tid == 0) {
            wsO[(isf ? 0 : 64) + b1] = o1;
            wsO[(isf ? 0 : 64) + b2] = o2;
        }
    }
}

__global__ __launch_bounds__(64)
void crf_combine(const float* __restrict__ wsV, const int* __restrict__ wsO,
                 const int* __restrict__ lengths, float* __restrict__ out)
{
    const int b = blockIdx.x;
    const int g = threadIdx.x;   // 64 lanes, pair {2g,2g+1}
    f2 a = *reinterpret_cast<const f2*>(wsV + (size_t)b * 128 + 2 * g);
    f2 x = *reinterpret_cast<const f2*>(wsV + (size_t)(64 + b) * 128 + 2 * g);
    float v = a.x * x.x + a.y * x.y;
    #pragma unroll
    for (int s = 1; s < 64; s <<= 1) v += __shfl_xor(v, s);
    if (g == 0)
        out[b] = LN2 * ((float)(wsO[b] + wsO[64 + b]) +
                        __builtin_amdgcn_logf(v));
}

extern "C" void kernel_launch(void* const* d_in, const int* in_sizes, int n_in,
                              void* d_out, int out_size, void* d_ws, size_t ws_size,
                              hipStream_t stream) {
    const float* emissions   = (const float*)d_in[0];
    const float* transitions = (const float*)d_in[1];
    const float* start_t     = (const float*)d_in[2];
    const float* end_t       = (const float*)d_in[3];
    const int*   lengths     = (const int*)d_in[4];
    float* out = (float*)d_out;

    float* wsV = (float*)d_ws;                                   // [2][64][128]
    int*   wsO = (int*)((char*)d_ws + 2 * 64 * 128 * sizeof(float)); // [2][64]

    crf_halves<<<dim3(64), dim3(256), 0, stream>>>(
        emissions, transitions, start_t, end_t, lengths, wsV, wsO);
    crf_combine<<<dim3(64), dim3(64), 0, stream>>>(wsV, wsO, lengths, out);
}

// Round 7
// 167.825 us; speedup vs baseline: 1.6535x; 1.0973x over previous
//
#include <hip/hip_runtime.h>

// CRF log-partition, MI355X — R6: partial-sum reduction instead of state broadcast.
// R5 lesson: chains are already wall-parallel across blocks; pairing only
// serializes issue. Back to 128 blocks (1 chain each), attacking R2's 648-cyc
// step, whose dominant term is the cross-wave STATE exchange (write + flush +
// barrier + 120cyc b128 read).  Remap of work:
//   wave w owns i-chunk [32w, 32w+32)  (pair-dwords m in [16w,16w+16))
//   lane l (0..63) owns column-pair {2l, 2l+1}
// Per step:
//   - 16 intra-wave ds_bpermute broadcast the chunk's state dwords from the
//     lanes that hold them (register crossbar: no LDS store, no barrier)
//   - 32 fdot2/lane (16 pair-dwords x 2 cols), 4 chains (same count as R2)
//   - cross-wave traffic is ONLY a 4-way f32 partial reduction:
//     ds_write_b64 -> lgkm+barrier -> 2x b128 read -> 6 adds
//   - renormalizer: OLD q0 carried in an SGPR via readfirstlane (lane 0 of
//     every wave computes identical q_0) -> eS extraction is scalar; exp2
//     arg folding identical to R1-R5 (validated); o += eS exact
//   - state q_l lives in registers; lane l writes the final f32 pair once
// E tile: 32 NAMED h2 regs per lane (R2-proven, no AGPR parking).
// Double-buffered reduction scratch, ONE lgkm-only barrier per step; the
// distance-4 emission prefetch ring (vmcnt stays untouched) is retained.
// Bidi split (R2-validated) + crf_combine unchanged.

#define LOG2E 1.4426950408889634f
#define LN2   0.6931471805599453f

#define LDS_BARRIER() asm volatile("s_waitcnt lgkmcnt(0)\n\ts_barrier" ::: "memory")

typedef float    f2 __attribute__((ext_vector_type(2)));
typedef float    f4 __attribute__((ext_vector_type(4)));
typedef _Float16 h2 __attribute__((ext_vector_type(2)));

#define PKRTZ(a, b) __builtin_bit_cast(h2, __builtin_amdgcn_cvt_pkrtz((a), (b)))

__global__ __launch_bounds__(256)
__attribute__((amdgpu_waves_per_eu(1, 1)))
void crf_halves(
    const float* __restrict__ emissions,   // [64, 512, 128]
    const float* __restrict__ transitions, // [128, 128]
    const float* __restrict__ start_t,     // [128]
    const float* __restrict__ end_t,       // [128]
    const int*   __restrict__ lengths,     // [64]
    float* __restrict__ wsV,               // [2][64][128] half-vectors
    int*   __restrict__ wsO)               // [2][64] exponent accumulators
{
    constexpr int N = 128;
    constexpr int L = 512;
    const int  bid = blockIdx.x;
    const bool isf = bid < 64;
    const int  b   = isf ? bid : bid - 64;
    const int  tid = threadIdx.x;
    const int  w   = tid >> 6;        // wave = i-chunk [32w, 32w+32)
    const int  l   = tid & 63;        // lane = column-pair {2l, 2l+1}

    // reduction scratch: [buf][l][2w..2w+1] f32 partials, 32B/lane row
    __shared__ alignas(16) float P_red[2][64][8];

    // ---- E tile: 32 NAMED h2 regs. j in [0,16), pair-dword m = 16w+j.
    // fwd: EA_j = (e^T[2m][2l],   e^T[2m+1][2l]),  EB_j: col 2l+1
    // bwd: EA_j = (e^T[2l][2m],   e^T[2l][2m+1]),  EB_j: row 2l+1
    h2 EA_0,  EA_1,  EA_2,  EA_3,  EA_4,  EA_5,  EA_6,  EA_7;
    h2 EA_8,  EA_9,  EA_10, EA_11, EA_12, EA_13, EA_14, EA_15;
    h2 EB_0,  EB_1,  EB_2,  EB_3,  EB_4,  EB_5,  EB_6,  EB_7;
    h2 EB_8,  EB_9,  EB_10, EB_11, EB_12, EB_13, EB_14, EB_15;
    if (isf) {
        const float* tb = transitions + (size_t)(32 * w) * N + 2 * l;
#define INIT_F(j)                                                              \
        {                                                                      \
            f2 r0 = *reinterpret_cast<const f2*>(tb + (size_t)(2 * (j)) * N);  \
            f2 r1 = *reinterpret_cast<const f2*>(tb + (size_t)(2 * (j) + 1) * N); \
            EA_##j = PKRTZ(__builtin_amdgcn_exp2f(r0.x * LOG2E),               \
                           __builtin_amdgcn_exp2f(r1.x * LOG2E));              \
            EB_##j = PKRTZ(__builtin_amdgcn_exp2f(r0.y * LOG2E),               \
                           __builtin_amdgcn_exp2f(r1.y * LOG2E));              \
        }
        INIT_F(0)  INIT_F(1)  INIT_F(2)  INIT_F(3)
        INIT_F(4)  INIT_F(5)  INIT_F(6)  INIT_F(7)
        INIT_F(8)  INIT_F(9)  INIT_F(10) INIT_F(11)
        INIT_F(12) INIT_F(13) INIT_F(14) INIT_F(15)
#undef INIT_F
    } else {
        const float* ra_ = transitions + (size_t)(2 * l) * N + 32 * w;
        const float* rb_ = transitions + (size_t)(2 * l + 1) * N + 32 * w;
#define INIT_B(j)                                                              \
        {                                                                      \
            f2 r0 = *reinterpret_cast<const f2*>(ra_ + 2 * (j));               \
            f2 r1 = *reinterpret_cast<const f2*>(rb_ + 2 * (j));               \
            EA_##j = PKRTZ(__builtin_amdgcn_exp2f(r0.x * LOG2E),               \
                           __builtin_amdgcn_exp2f(r0.y * LOG2E));              \
            EB_##j = PKRTZ(__builtin_amdgcn_exp2f(r1.x * LOG2E),               \
                           __builtin_amdgcn_exp2f(r1.y * LOG2E));              \
        }
        INIT_B(0)  INIT_B(1)  INIT_B(2)  INIT_B(3)
        INIT_B(4)  INIT_B(5)  INIT_B(6)  INIT_B(7)
        INIT_B(8)  INIT_B(9)  INIT_B(10) INIT_B(11)
        INIT_B(12) INIT_B(13) INIT_B(14) INIT_B(15)
#undef INIT_B
    }

    const int len = lengths[b];
    const int m   = (len - 1) >> 1;
    const float* eb = emissions + (size_t)b * L * N;

    // step schedule (validated R2-R5)
    int n_steps, e0, dstep; bool zfinal;
    if (isf) {
        n_steps = m; e0 = 1; dstep = 1; zfinal = false;
    } else {
        int total = len - 1 - m;
        n_steps = total > 0 ? total - 1 : 0;
        e0 = len - 2; if (e0 < 0) e0 = 0;
        dstep = -1;
        zfinal = total > 0;
    }

    // ---- init state: lane l holds q for pair l, packed f16 in qpk
    int o = 0, cur = 0;
    float qA, qB;
    int qpk, sq0;
    {
        const float* base = isf ? start_t : end_t;
        f2 bt = *reinterpret_cast<const f2*>(base + 2 * l);
        f2 ev;
        if (isf)         ev = *reinterpret_cast<const f2*>(eb + 2 * l);
        else if (zfinal) ev = *reinterpret_cast<const f2*>(eb + (size_t)(len - 1) * N + 2 * l);
        else           { ev.x = 0.f; ev.y = 0.f; }
        qA = __builtin_amdgcn_exp2f((bt.x + ev.x) * LOG2E);
        qB = __builtin_amdgcn_exp2f((bt.y + ev.y) * LOG2E);
        qpk = __builtin_bit_cast(int, PKRTZ(qA, qB));
        sq0 = __builtin_amdgcn_readfirstlane(qpk);
    }

    auto eidx = [&](int n) {
        int nn = (n < n_steps) ? n : (n_steps - 1);
        if (nn < 0) nn = 0;
        return e0 + dstep * nn;
    };
    auto ldE = [&](int tt) {
        return *reinterpret_cast<const f2*>(eb + (size_t)tt * N + 2 * l);
    };

    auto STEP = [&](f2 ecur) {
        // intra-wave state broadcast: chunk pair-dwords from lanes 16w+j
        int P0  = __builtin_amdgcn_ds_bpermute((16 * w + 0)  * 4, qpk);
        int P1  = __builtin_amdgcn_ds_bpermute((16 * w + 1)  * 4, qpk);
        int P2  = __builtin_amdgcn_ds_bpermute((16 * w + 2)  * 4, qpk);
        int P3  = __builtin_amdgcn_ds_bpermute((16 * w + 3)  * 4, qpk);
        int P4  = __builtin_amdgcn_ds_bpermute((16 * w + 4)  * 4, qpk);
        int P5  = __builtin_amdgcn_ds_bpermute((16 * w + 5)  * 4, qpk);
        int P6  = __builtin_amdgcn_ds_bpermute((16 * w + 6)  * 4, qpk);
        int P7  = __builtin_amdgcn_ds_bpermute((16 * w + 7)  * 4, qpk);
        int P8  = __builtin_amdgcn_ds_bpermute((16 * w + 8)  * 4, qpk);
        int P9  = __builtin_amdgcn_ds_bpermute((16 * w + 9)  * 4, qpk);
        int P10 = __builtin_amdgcn_ds_bpermute((16 * w + 10) * 4, qpk);
        int P11 = __builtin_amdgcn_ds_bpermute((16 * w + 11) * 4, qpk);
        int P12 = __builtin_amdgcn_ds_bpermute((16 * w + 12) * 4, qpk);
        int P13 = __builtin_amdgcn_ds_bpermute((16 * w + 13) * 4, qpk);
        int P14 = __builtin_amdgcn_ds_bpermute((16 * w + 14) * 4, qpk);
        int P15 = __builtin_amdgcn_ds_bpermute((16 * w + 15) * 4, qpk);

        // renorm factors from OLD q0 (SGPR) + emission — off the LDS path
        int eS = ((sq0 >> 10) & 31) - 15;
        o += eS;
        float feS = (float)eS;
        float esA = __builtin_amdgcn_exp2f(ecur.x * LOG2E - feS);
        float esB = __builtin_amdgcn_exp2f(ecur.y * LOG2E - feS);

        // 32 fdot2, 4 chains (depth 8)
        float aA0 = 0.f, aA1 = 0.f, aB0 = 0.f, aB1 = 0.f;
#define DJ(j0, j1, Pa, Pb)                                                     \
        {                                                                      \
            h2 pa = __builtin_bit_cast(h2, Pa);                                \
            h2 pb = __builtin_bit_cast(h2, Pb);                                \
            aA0 = __builtin_amdgcn_fdot2(pa, EA_##j0, aA0, false);             \
            aB0 = __builtin_amdgcn_fdot2(pa, EB_##j0, aB0, false);             \
            aA1 = __builtin_amdgcn_fdot2(pb, EA_##j1, aA1, false);             \
            aB1 = __builtin_amdgcn_fdot2(pb, EB_##j1, aB1, false);             \
        }
        DJ(0,  1,  P0,  P1)  DJ(2,  3,  P2,  P3)
        DJ(4,  5,  P4,  P5)  DJ(6,  7,  P6,  P7)
        DJ(8,  9,  P8,  P9)  DJ(10, 11, P10, P11)
        DJ(12, 13, P12, P13) DJ(14, 15, P14, P15)
#undef DJ

        // cross-wave 4-way partial reduction (the ONLY barrier per step)
        f2 part; part.x = aA0 + aA1; part.y = aB0 + aB1;
        cur ^= 1;
        *reinterpret_cast<f2*>(&P_red[cur][l][2 * w]) = part;
        LDS_BARRIER();
        f4 r01 = *reinterpret_cast<const f4*>(&P_red[cur][l][0]);
        f4 r23 = *reinterpret_cast<const f4*>(&P_red[cur][l][4]);
        float dA = (r01.x + r01.z) + (r23.x + r23.z);
        float dB = (r01.y + r01.w) + (r23.y + r23.w);

        qA = esA * dA;
        qB = esB * dB;
        qpk = __builtin_bit_cast(int, PKRTZ(qA, qB));
        sq0 = __builtin_amdgcn_readfirstlane(qpk);
    };

    // ---- main loop: distance-4 emission prefetch ring, 4-way unroll
    f2 ra = ldE(eidx(0));
    f2 rb = ldE(eidx(1));
    f2 rc = ldE(eidx(2));
    f2 rd = ldE(eidx(3));

    int n = 0;
    while (n < n_steps) {
        STEP(ra); ra = ldE(eidx(n + 4)); ++n; if (n >= n_steps) break;
        STEP(rb); rb = ldE(eidx(n + 4)); ++n; if (n >= n_steps) break;
        STEP(rc); rc = ldE(eidx(n + 4)); ++n; if (n >= n_steps) break;
        STEP(rd); rd = ldE(eidx(n + 4)); ++n;
    }
    if (zfinal) {              // x_m = E * w_{m+1}: zero-emission step
        f2 z; z.x = 0.f; z.y = 0.f;
        STEP(z);
    }

    // ---- write half-result: lane l's f32 pair (wave 0 only) + exponent
    if (w == 0) {
        float* wv = wsV + (size_t)((isf ? 0 : 64) + b) * 128;
        f2 q; q.x = qA; q.y = qB;
        *reinterpret_cast<f2*>(wv + 2 * l) = q;
    }
    if (tid == 0) wsO[(isf ? 0 : 64) + b] = o;
}

__global__ __launch_bounds__(64)
void crf_combine(const float* __restrict__ wsV, const int* __restrict__ wsO,
                 const int* __restrict__ lengths, float* __restrict__ out)
{
    const int b = blockIdx.x;
    const int g = threadIdx.x;   // 64 lanes, pair {2g,2g+1}
    f2 a = *reinterpret_cast<const f2*>(wsV + (size_t)b * 128 + 2 * g);
    f2 x = *reinterpret_cast<const f2*>(wsV + (size_t)(64 + b) * 128 + 2 * g);
    float v = a.x * x.x + a.y * x.y;
    #pragma unroll
    for (int s = 1; s < 64; s <<= 1) v += __shfl_xor(v, s);
    if (g == 0)
        out[b] = LN2 * ((float)(wsO[b] + wsO[64 + b]) +
                        __builtin_amdgcn_logf(v));
}

extern "C" void kernel_launch(void* const* d_in, const int* in_sizes, int n_in,
                              void* d_out, int out_size, void* d_ws, size_t ws_size,
                              hipStream_t stream) {
    const float* emissions   = (const float*)d_in[0];
    const float* transitions = (const float*)d_in[1];
    const float* start_t     = (const float*)d_in[2];
    const float* end_t       = (const float*)d_in[3];
    const int*   lengths     = (const int*)d_in[4];
    float* out = (float*)d_out;

    float* wsV = (float*)d_ws;                                   // [2][64][128]
    int*   wsO = (int*)((char*)d_ws + 2 * 64 * 128 * sizeof(float)); // [2][64]

    crf_halves<<<dim3(128), dim3(256), 0, stream>>>(
        emissions, transitions, start_t, end_t, lengths, wsV, wsO);
    crf_combine<<<dim3(64), dim3(64), 0, stream>>>(wsV, wsO, lengths, out);
}